// Round 1
// 320.961 us; speedup vs baseline: 1.0562x; 1.0562x over previous
//
#include <hip/hip_runtime.h>

// Pairwise Euclidean distance: out[i][j] = ||x_i - y_j||,
// x: [4096, 256] fp32, y: [16384, 256] fp32, out: [4096, 16384] fp32.
// d2 = x2 + y2 - 2*<x,y>; cross term via bf16 MFMA, norms in fp32.
//
// R1: pre-convert x/y to bf16 once (prep kernel, fused with norms) into the
// 1 GiB workspace; GEMM stages bf16 directly via global_load_lds (width=16)
// with XOR-swizzled per-lane global source (linear LDS dest), m97 structure.

using bf16x8   = __attribute__((ext_vector_type(8))) short;
using f32x4    = __attribute__((ext_vector_type(4))) float;
using ushort4v = __attribute__((ext_vector_type(4))) unsigned short;

constexpr int NXR = 4096;    // rows of x
constexpr int NYR = 16384;   // rows of y
constexpr int DD  = 256;     // feature dim

constexpr int BM = 128;      // x-rows per block
constexpr int BN = 128;      // y-rows per block
constexpr int BK = 64;       // K slice per stage (4 K-steps total)

__device__ inline unsigned short f2bf(float f) {
    unsigned int b = __float_as_uint(f);
    b += 0x7FFFu + ((b >> 16) & 1u);   // RNE
    return (unsigned short)(b >> 16);
}

__device__ inline void gl_lds16(const void* g, void* l) {
    __builtin_amdgcn_global_load_lds(
        (const __attribute__((address_space(1))) void*)g,
        (__attribute__((address_space(3))) void*)l, 16, 0, 0);
}

// ---------------- prep: ws[0..4096)=||x_i||^2, ws[4096..20480)=||y_j||^2,
// then xb (bf16 4096x256) and yb (bf16 16384x256), row-major.
__global__ __launch_bounds__(256) void prep_kernel(const float* __restrict__ x,
                                                   const float* __restrict__ y,
                                                   float* __restrict__ ws) {
    float* xn = ws;
    float* yn = ws + NXR;
    unsigned short* xb = (unsigned short*)(ws + NXR + NYR);
    unsigned short* yb = xb + (size_t)NXR * DD;

    const int row  = blockIdx.x * 4 + (threadIdx.x >> 6);   // one wave per row
    const int lane = threadIdx.x & 63;
    const bool isx = row < NXR;
    const int  r   = isx ? row : row - NXR;
    const float* src        = (isx ? x  : y ) + (size_t)r * DD;
    unsigned short* dst     = (isx ? xb : yb) + (size_t)r * DD;

    float4 v = *(const float4*)(src + lane * 4);            // 64 lanes x 4 = 256
    ushort4v b = { f2bf(v.x), f2bf(v.y), f2bf(v.z), f2bf(v.w) };
    *(ushort4v*)(dst + lane * 4) = b;

    float s = v.x * v.x + v.y * v.y + v.z * v.z + v.w * v.w;
    #pragma unroll
    for (int off = 32; off > 0; off >>= 1) s += __shfl_down(s, off, 64);
    if (lane == 0) (isx ? xn : yn)[r] = s;
}

// ---------------- main distance kernel (m97 structure, 4 waves, 128x128 tile)
__global__ __launch_bounds__(256) void dist_kernel(const float* __restrict__ ws,
                                                   float* __restrict__ out) {
    __shared__ unsigned short lA[BM * BK];   // 16 KB, linear, XOR-swizzled content
    __shared__ unsigned short lB[BN * BK];   // 16 KB

    const float* xn = ws;
    const float* yn = ws + NXR;
    const unsigned short* xb = (const unsigned short*)(ws + NXR + NYR);
    const unsigned short* yb = xb + (size_t)NXR * DD;

    // XCD-aware swizzle (4096 blocks, 8 XCDs, bijective). Within each XCD
    // chunk of 512 blocks: bm-fastest (4 bm x 128 bn) so the 4 x-panels stay
    // L2-hot while yb streams through once.
    const int bid = blockIdx.x;
    const int xcd = bid & 7;
    const int loc = bid >> 3;                 // 0..511
    const int bm  = xcd * 4 + (loc & 3);      // 0..31
    const int bn  = loc >> 2;                 // 0..127

    const int tid  = threadIdx.x;
    const int wave = tid >> 6;                // 0..3
    const int lane = tid & 63;
    const int wm   = wave & 1;                // 2 waves in M
    const int wn   = wave >> 1;               // 2 waves in N
    const int quad = lane >> 4;
    const int l15  = lane & 15;

    // Staging: global_load_lds dest is wave-uniform base + lane*16 (linear).
    // LDS (row, phys_slot) must hold logical slot = phys_slot ^ (row & 7)
    // => per-lane global source uses swizzled slot sl.
    const int rl = lane >> 3;                 // row within 8-row inst group (= row&7)
    const int sl = (lane & 7) ^ rl;           // swizzled 16B-slot in global
    const unsigned short* ag = xb + (size_t)(bm * BM + wave * 32 + rl) * DD + sl * 8;
    const unsigned short* bg = yb + (size_t)(bn * BN + wave * 32 + rl) * DD + sl * 8;

    f32x4 acc[4][4];
    #pragma unroll
    for (int i = 0; i < 4; ++i)
        #pragma unroll
        for (int j = 0; j < 4; ++j)
            acc[i][j] = f32x4{0.f, 0.f, 0.f, 0.f};

    const int arow = wm * 64 + l15;
    const int brow = wn * 64 + l15;
    const int s7   = l15 & 7;                 // row&7 for fragment rows (i*16 keeps it)

    #pragma unroll
    for (int kt = 0; kt < 4; ++kt) {
        if (kt) __syncthreads();              // prev compute done before overwrite
        // ---- stage A,B tiles: 16 insts each, 4 per wave (8 gload_lds/wave)
        #pragma unroll
        for (int q = 0; q < 4; ++q) {
            gl_lds16(ag + (size_t)q * 8 * DD + kt * BK, &lA[(wave * 4 + q) * 512]);
            gl_lds16(bg + (size_t)q * 8 * DD + kt * BK, &lB[(wave * 4 + q) * 512]);
        }
        __syncthreads();                      // compiler emits vmcnt(0) drain here
        // ---- compute: 2 k-slices of 16x16x32 MFMA, 4x4 frags/wave
        #pragma unroll
        for (int kk = 0; kk < 2; ++kk) {
            const int ka = (((kk << 2) | quad) ^ s7) << 3;   // swizzled ushort offset
            bf16x8 av[4], bv[4];
            #pragma unroll
            for (int i = 0; i < 4; ++i)
                av[i] = *(const bf16x8*)&lA[(arow + i * 16) * BK + ka];
            #pragma unroll
            for (int j = 0; j < 4; ++j)
                bv[j] = *(const bf16x8*)&lB[(brow + j * 16) * BK + ka];
            #pragma unroll
            for (int i = 0; i < 4; ++i)
                #pragma unroll
                for (int j = 0; j < 4; ++j)
                    acc[i][j] = __builtin_amdgcn_mfma_f32_16x16x32_bf16(
                        av[i], bv[j], acc[i][j], 0, 0, 0);
        }
    }

    // ---- epilogue: d = sqrt(max(x2 + y2 - 2*xy, 0))
    const int gr_base = bm * BM + wm * 64;
    const int gc_base = bn * BN + wn * 64;
    float ynv[4];
    #pragma unroll
    for (int j = 0; j < 4; ++j) ynv[j] = yn[gc_base + j * 16 + l15];
    #pragma unroll
    for (int i = 0; i < 4; ++i) {
        const int gr0 = gr_base + i * 16 + quad * 4;
        #pragma unroll
        for (int r = 0; r < 4; ++r) {
            const float xv = xn[gr0 + r];
            float* op = out + (size_t)(gr0 + r) * NYR + gc_base;
            #pragma unroll
            for (int j = 0; j < 4; ++j) {
                const float d2 = xv + ynv[j] - 2.0f * acc[i][j][r];
                op[j * 16 + l15] = sqrtf(fmaxf(d2, 0.0f));
            }
        }
    }
}

extern "C" void kernel_launch(void* const* d_in, const int* in_sizes, int n_in,
                              void* d_out, int out_size, void* d_ws, size_t ws_size,
                              hipStream_t stream) {
    const float* x = (const float*)d_in[0];
    const float* y = (const float*)d_in[1];
    float* ws  = (float*)d_ws;   // [0,4096): x2, [4096,20480): y2, then xb/yb bf16
    float* out = (float*)d_out;

    prep_kernel<<<(NXR + NYR) / 4, 256, 0, stream>>>(x, y, ws);
    dist_kernel<<<(NXR / BM) * (NYR / BN), 256, 0, stream>>>(ws, out);
}

// Round 2
// 312.059 us; speedup vs baseline: 1.0863x; 1.0285x over previous
//
#include <hip/hip_runtime.h>

// Pairwise Euclidean distance: out[i][j] = ||x_i - y_j||,
// x: [4096, 256] fp32, y: [16384, 256] fp32, out: [4096, 16384] fp32.
// d2 = x2 + y2 - 2*<x,y>; cross term via bf16 MFMA, norms in fp32.
//
// R2: epilogue rewritten for full-cache-line output stores. Each wave
// transposes its 16x64 f32 slab through padded LDS (reusing the staging
// buffer post-barrier) and emits f32x4 nontemporal stores: 4 rows x 256 B
// contiguous per instruction (2 full 128 B lines/row) -> no partial-line
// RFO, no L2 pollution of the bf16 panels. GEMM pipeline unchanged.

using bf16x8   = __attribute__((ext_vector_type(8))) short;
using f32x4    = __attribute__((ext_vector_type(4))) float;
using ushort4v = __attribute__((ext_vector_type(4))) unsigned short;

constexpr int NXR = 4096;    // rows of x
constexpr int NYR = 16384;   // rows of y
constexpr int DD  = 256;     // feature dim

constexpr int BM = 128;      // x-rows per block
constexpr int BN = 128;      // y-rows per block
constexpr int BK = 64;       // K slice per stage (4 K-steps total)
constexpr int EPD = 68;      // padded epilogue slab row (f32): 16x68 per wave

__device__ inline unsigned short f2bf(float f) {
    unsigned int b = __float_as_uint(f);
    b += 0x7FFFu + ((b >> 16) & 1u);   // RNE
    return (unsigned short)(b >> 16);
}

__device__ inline void gl_lds16(const void* g, void* l) {
    __builtin_amdgcn_global_load_lds(
        (const __attribute__((address_space(1))) void*)g,
        (__attribute__((address_space(3))) void*)l, 16, 0, 0);
}

// ---------------- prep: ws[0..4096)=||x_i||^2, ws[4096..20480)=||y_j||^2,
// then xb (bf16 4096x256) and yb (bf16 16384x256), row-major.
__global__ __launch_bounds__(256) void prep_kernel(const float* __restrict__ x,
                                                   const float* __restrict__ y,
                                                   float* __restrict__ ws) {
    float* xn = ws;
    float* yn = ws + NXR;
    unsigned short* xb = (unsigned short*)(ws + NXR + NYR);
    unsigned short* yb = xb + (size_t)NXR * DD;

    const int row  = blockIdx.x * 4 + (threadIdx.x >> 6);   // one wave per row
    const int lane = threadIdx.x & 63;
    const bool isx = row < NXR;
    const int  r   = isx ? row : row - NXR;
    const float* src        = (isx ? x  : y ) + (size_t)r * DD;
    unsigned short* dst     = (isx ? xb : yb) + (size_t)r * DD;

    float4 v = *(const float4*)(src + lane * 4);            // 64 lanes x 4 = 256
    ushort4v b = { f2bf(v.x), f2bf(v.y), f2bf(v.z), f2bf(v.w) };
    *(ushort4v*)(dst + lane * 4) = b;

    float s = v.x * v.x + v.y * v.y + v.z * v.z + v.w * v.w;
    #pragma unroll
    for (int off = 32; off > 0; off >>= 1) s += __shfl_down(s, off, 64);
    if (lane == 0) (isx ? xn : yn)[r] = s;
}

// ---------------- main distance kernel (m97 structure, 4 waves, 128x128 tile)
__global__ __launch_bounds__(256) void dist_kernel(const float* __restrict__ ws,
                                                   float* __restrict__ out) {
    // 32 KB: bf16 staging tiles during GEMM; f32 transpose scratch in epilogue.
    __shared__ unsigned short smem[2 * BM * BK];
    unsigned short* lA = smem;                 // 16 KB
    unsigned short* lB = smem + BM * BK;       // 16 KB

    const float* xn = ws;
    const float* yn = ws + NXR;
    const unsigned short* xb = (const unsigned short*)(ws + NXR + NYR);
    const unsigned short* yb = xb + (size_t)NXR * DD;

    // XCD-aware swizzle (4096 blocks, 8 XCDs, bijective). Within each XCD
    // chunk: bm-fastest (4 bm x 128 bn) so the 4 x-panels stay L2-hot while
    // yb streams through once.
    const int bid = blockIdx.x;
    const int xcd = bid & 7;
    const int loc = bid >> 3;                 // 0..511
    const int bm  = xcd * 4 + (loc & 3);      // 0..31
    const int bn  = loc >> 2;                 // 0..127

    const int tid  = threadIdx.x;
    const int wave = tid >> 6;                // 0..3
    const int lane = tid & 63;
    const int wm   = wave & 1;                // 2 waves in M
    const int wn   = wave >> 1;               // 2 waves in N
    const int quad = lane >> 4;
    const int l15  = lane & 15;

    // Staging: global_load_lds dest is wave-uniform base + lane*16 (linear).
    // LDS (row, phys_slot) holds logical slot = phys_slot ^ (row & 7)
    // => per-lane global source uses swizzled slot sl.
    const int rl = lane >> 3;                 // row within 8-row inst group (= row&7)
    const int sl = (lane & 7) ^ rl;           // swizzled 16B-slot in global
    const unsigned short* ag = xb + (size_t)(bm * BM + wave * 32 + rl) * DD + sl * 8;
    const unsigned short* bg = yb + (size_t)(bn * BN + wave * 32 + rl) * DD + sl * 8;

    f32x4 acc[4][4];
    #pragma unroll
    for (int i = 0; i < 4; ++i)
        #pragma unroll
        for (int j = 0; j < 4; ++j)
            acc[i][j] = f32x4{0.f, 0.f, 0.f, 0.f};

    const int arow = wm * 64 + l15;
    const int brow = wn * 64 + l15;
    const int s7   = l15 & 7;                 // row&7 for fragment rows (i*16 keeps it)

    #pragma unroll
    for (int kt = 0; kt < 4; ++kt) {
        if (kt) __syncthreads();              // prev compute done before overwrite
        // ---- stage A,B tiles: 16 insts each, 4 per wave (8 gload_lds/wave)
        #pragma unroll
        for (int q = 0; q < 4; ++q) {
            gl_lds16(ag + (size_t)q * 8 * DD + kt * BK, &lA[(wave * 4 + q) * 512]);
            gl_lds16(bg + (size_t)q * 8 * DD + kt * BK, &lB[(wave * 4 + q) * 512]);
        }
        __syncthreads();                      // vmcnt(0) drain: tiles resident
        // ---- compute: 2 k-slices of 16x16x32 MFMA, 4x4 frags/wave
        #pragma unroll
        for (int kk = 0; kk < 2; ++kk) {
            const int ka = (((kk << 2) | quad) ^ s7) << 3;   // swizzled ushort offset
            bf16x8 av[4], bv[4];
            #pragma unroll
            for (int i = 0; i < 4; ++i)
                av[i] = *(const bf16x8*)&lA[(arow + i * 16) * BK + ka];
            #pragma unroll
            for (int j = 0; j < 4; ++j)
                bv[j] = *(const bf16x8*)&lB[(brow + j * 16) * BK + ka];
            #pragma unroll
            for (int i = 0; i < 4; ++i)
                #pragma unroll
                for (int j = 0; j < 4; ++j)
                    acc[i][j] = __builtin_amdgcn_mfma_f32_16x16x32_bf16(
                        av[i], bv[j], acc[i][j], 0, 0, 0);
        }
    }

    // ---- epilogue: d = sqrt(max(x2 + y2 - 2*xy, 0)), full-line stores.
    __syncthreads();                          // staging done; reuse smem as f32 scratch
    float* ep = ((float*)smem) + wave * (16 * EPD);   // 16x68 f32 slab per wave

    const int gr_base = bm * BM + wm * 64;
    const int gc_base = bn * BN + wn * 64;
    float ynv[4];
    #pragma unroll
    for (int j = 0; j < 4; ++j) ynv[j] = yn[gc_base + j * 16 + l15];

    #pragma unroll
    for (int i = 0; i < 4; ++i) {
        // scatter this 16x64 slab into padded LDS (2-way bank alias = free)
        #pragma unroll
        for (int r = 0; r < 4; ++r) {
            const int row = quad * 4 + r;
            const float xv = xn[gr_base + i * 16 + row];
            #pragma unroll
            for (int j = 0; j < 4; ++j) {
                const float d2 = xv + ynv[j] - 2.0f * acc[i][j][r];
                ep[row * EPD + j * 16 + l15] = sqrtf(fmaxf(d2, 0.0f));
            }
        }
        // gather rows: each inst = 4 rows x 256 B contiguous (full lines), nt
        #pragma unroll
        for (int s = 0; s < 4; ++s) {
            const int row = s * 4 + quad;
            f32x4 v = *(const f32x4*)&ep[row * EPD + l15 * 4];
            float* op = out + (size_t)(gr_base + i * 16 + row) * NYR + gc_base + l15 * 4;
            __builtin_nontemporal_store(v, (f32x4*)op);
        }
    }
}

extern "C" void kernel_launch(void* const* d_in, const int* in_sizes, int n_in,
                              void* d_out, int out_size, void* d_ws, size_t ws_size,
                              hipStream_t stream) {
    const float* x = (const float*)d_in[0];
    const float* y = (const float*)d_in[1];
    float* ws  = (float*)d_ws;   // [0,4096): x2, [4096,20480): y2, then xb/yb bf16
    float* out = (float*)d_out;

    prep_kernel<<<(NXR + NYR) / 4, 256, 0, stream>>>(x, y, ws);
    dist_kernel<<<(NXR / BM) * (NYR / BN), 256, 0, stream>>>(ws, out);
}

// Round 3
// 295.713 us; speedup vs baseline: 1.1464x; 1.0553x over previous
//
#include <hip/hip_runtime.h>

// Pairwise Euclidean distance: out[i][j] = ||x_i - y_j||,
// x: [4096, 256] fp32, y: [16384, 256] fp32, out: [4096, 16384] fp32.
// d2 = x2 + y2 - 2*<x,y>; cross term via bf16 MFMA, norms in fp32.
//
// R3: epilogue math slimmed. prep stores bf16(-2*y) (exact scaling), so
// d2 = x2 + y2 + acc -> one v_add3_f32; raw v_sqrt_f32 via builtin instead
// of libm sqrtf; __launch_bounds__(256,4) pins dist at <=128 VGPR so 16
// waves/CU are guaranteed. GEMM pipeline and store path unchanged from R2.

using bf16x8   = __attribute__((ext_vector_type(8))) short;
using f32x4    = __attribute__((ext_vector_type(4))) float;
using ushort4v = __attribute__((ext_vector_type(4))) unsigned short;

constexpr int NXR = 4096;    // rows of x
constexpr int NYR = 16384;   // rows of y
constexpr int DD  = 256;     // feature dim

constexpr int BM = 128;      // x-rows per block
constexpr int BN = 128;      // y-rows per block
constexpr int BK = 64;       // K slice per stage (4 K-steps total)
constexpr int EPD = 68;      // padded epilogue slab row (f32): 16x68 per wave

__device__ inline unsigned short f2bf(float f) {
    unsigned int b = __float_as_uint(f);
    b += 0x7FFFu + ((b >> 16) & 1u);   // RNE
    return (unsigned short)(b >> 16);
}

__device__ inline void gl_lds16(const void* g, void* l) {
    __builtin_amdgcn_global_load_lds(
        (const __attribute__((address_space(1))) void*)g,
        (__attribute__((address_space(3))) void*)l, 16, 0, 0);
}

// ---------------- prep: ws[0..4096)=||x_i||^2, ws[4096..20480)=||y_j||^2,
// then xb = bf16(x) [4096x256] and yb = bf16(-2*y) [16384x256], row-major.
// (-2 scaling is exact in bf16: sign flip + exponent+1, no mantissa change.)
__global__ __launch_bounds__(256) void prep_kernel(const float* __restrict__ x,
                                                   const float* __restrict__ y,
                                                   float* __restrict__ ws) {
    float* xn = ws;
    float* yn = ws + NXR;
    unsigned short* xb = (unsigned short*)(ws + NXR + NYR);
    unsigned short* yb = xb + (size_t)NXR * DD;

    const int row  = blockIdx.x * 4 + (threadIdx.x >> 6);   // one wave per row
    const int lane = threadIdx.x & 63;
    const bool isx = row < NXR;
    const int  r   = isx ? row : row - NXR;
    const float* src        = (isx ? x  : y ) + (size_t)r * DD;
    unsigned short* dst     = (isx ? xb : yb) + (size_t)r * DD;

    float4 v = *(const float4*)(src + lane * 4);            // 64 lanes x 4 = 256
    const float sc_ = isx ? 1.0f : -2.0f;                   // fold -2 into y
    ushort4v b = { f2bf(v.x * sc_), f2bf(v.y * sc_),
                   f2bf(v.z * sc_), f2bf(v.w * sc_) };
    *(ushort4v*)(dst + lane * 4) = b;

    float s = v.x * v.x + v.y * v.y + v.z * v.z + v.w * v.w; // norms unscaled
    #pragma unroll
    for (int off = 32; off > 0; off >>= 1) s += __shfl_down(s, off, 64);
    if (lane == 0) (isx ? xn : yn)[r] = s;
}

// ---------------- main distance kernel (m97 structure, 4 waves, 128x128 tile)
__global__ __launch_bounds__(256, 4) void dist_kernel(const float* __restrict__ ws,
                                                      float* __restrict__ out) {
    // 32 KB: bf16 staging tiles during GEMM; f32 transpose scratch in epilogue.
    __shared__ unsigned short smem[2 * BM * BK];
    unsigned short* lA = smem;                 // 16 KB
    unsigned short* lB = smem + BM * BK;       // 16 KB

    const float* xn = ws;
    const float* yn = ws + NXR;
    const unsigned short* xb = (const unsigned short*)(ws + NXR + NYR);
    const unsigned short* yb = xb + (size_t)NXR * DD;

    // XCD-aware swizzle (4096 blocks, 8 XCDs, bijective). Within each XCD
    // chunk: bm-fastest (4 bm x 128 bn) so the 4 x-panels stay L2-hot while
    // yb streams through once.
    const int bid = blockIdx.x;
    const int xcd = bid & 7;
    const int loc = bid >> 3;                 // 0..511
    const int bm  = xcd * 4 + (loc & 3);      // 0..31
    const int bn  = loc >> 2;                 // 0..127

    const int tid  = threadIdx.x;
    const int wave = tid >> 6;                // 0..3
    const int lane = tid & 63;
    const int wm   = wave & 1;                // 2 waves in M
    const int wn   = wave >> 1;               // 2 waves in N
    const int quad = lane >> 4;
    const int l15  = lane & 15;

    // Staging: global_load_lds dest is wave-uniform base + lane*16 (linear).
    // LDS (row, phys_slot) holds logical slot = phys_slot ^ (row & 7)
    // => per-lane global source uses swizzled slot sl.
    const int rl = lane >> 3;                 // row within 8-row inst group (= row&7)
    const int sl = (lane & 7) ^ rl;           // swizzled 16B-slot in global
    const unsigned short* ag = xb + (size_t)(bm * BM + wave * 32 + rl) * DD + sl * 8;
    const unsigned short* bg = yb + (size_t)(bn * BN + wave * 32 + rl) * DD + sl * 8;

    f32x4 acc[4][4];
    #pragma unroll
    for (int i = 0; i < 4; ++i)
        #pragma unroll
        for (int j = 0; j < 4; ++j)
            acc[i][j] = f32x4{0.f, 0.f, 0.f, 0.f};

    const int arow = wm * 64 + l15;
    const int brow = wn * 64 + l15;
    const int s7   = l15 & 7;                 // row&7 for fragment rows (i*16 keeps it)

    #pragma unroll
    for (int kt = 0; kt < 4; ++kt) {
        if (kt) __syncthreads();              // prev compute done before overwrite
        // ---- stage A,B tiles: 16 insts each, 4 per wave (8 gload_lds/wave)
        #pragma unroll
        for (int q = 0; q < 4; ++q) {
            gl_lds16(ag + (size_t)q * 8 * DD + kt * BK, &lA[(wave * 4 + q) * 512]);
            gl_lds16(bg + (size_t)q * 8 * DD + kt * BK, &lB[(wave * 4 + q) * 512]);
        }
        __syncthreads();                      // vmcnt(0) drain: tiles resident
        // ---- compute: 2 k-slices of 16x16x32 MFMA, 4x4 frags/wave
        #pragma unroll
        for (int kk = 0; kk < 2; ++kk) {
            const int ka = (((kk << 2) | quad) ^ s7) << 3;   // swizzled ushort offset
            bf16x8 av[4], bv[4];
            #pragma unroll
            for (int i = 0; i < 4; ++i)
                av[i] = *(const bf16x8*)&lA[(arow + i * 16) * BK + ka];
            #pragma unroll
            for (int j = 0; j < 4; ++j)
                bv[j] = *(const bf16x8*)&lB[(brow + j * 16) * BK + ka];
            #pragma unroll
            for (int i = 0; i < 4; ++i)
                #pragma unroll
                for (int j = 0; j < 4; ++j)
                    acc[i][j] = __builtin_amdgcn_mfma_f32_16x16x32_bf16(
                        av[i], bv[j], acc[i][j], 0, 0, 0);
        }
    }

    // ---- epilogue: d = sqrt(max(x2 + y2 + (-2xy), 0)), full-line stores.
    // acc already holds -2<x,y> (y pre-scaled), so d2 is one v_add3_f32.
    __syncthreads();                          // staging done; reuse smem as f32 scratch
    float* ep = ((float*)smem) + wave * (16 * EPD);   // 16x68 f32 slab per wave

    const int gr_base = bm * BM + wm * 64;
    const int gc_base = bn * BN + wn * 64;
    float ynv[4];
    #pragma unroll
    for (int j = 0; j < 4; ++j) ynv[j] = yn[gc_base + j * 16 + l15];

    #pragma unroll
    for (int i = 0; i < 4; ++i) {
        // scatter this 16x64 slab into padded LDS (2-way bank alias = free)
        #pragma unroll
        for (int r = 0; r < 4; ++r) {
            const int row = quad * 4 + r;
            const float xv = xn[gr_base + i * 16 + row];
            #pragma unroll
            for (int j = 0; j < 4; ++j) {
                const float d2 = xv + ynv[j] + acc[i][j][r];    // v_add3_f32
                ep[row * EPD + j * 16 + l15] =
                    __builtin_amdgcn_sqrtf(fmaxf(d2, 0.0f));    // raw v_sqrt_f32
            }
        }
        // gather rows: each inst = 4 rows x 256 B contiguous (full lines), nt
        #pragma unroll
        for (int s = 0; s < 4; ++s) {
            const int row = s * 4 + quad;
            f32x4 v = *(const f32x4*)&ep[row * EPD + l15 * 4];
            float* op = out + (size_t)(gr_base + i * 16 + row) * NYR + gc_base + l15 * 4;
            __builtin_nontemporal_store(v, (f32x4*)op);
        }
    }
}

extern "C" void kernel_launch(void* const* d_in, const int* in_sizes, int n_in,
                              void* d_out, int out_size, void* d_ws, size_t ws_size,
                              hipStream_t stream) {
    const float* x = (const float*)d_in[0];
    const float* y = (const float*)d_in[1];
    float* ws  = (float*)d_ws;   // [0,4096): x2, [4096,20480): y2, then xb/yb bf16
    float* out = (float*)d_out;

    prep_kernel<<<(NXR + NYR) / 4, 256, 0, stream>>>(x, y, ws);
    dist_kernel<<<(NXR / BM) * (NYR / BN), 256, 0, stream>>>(ws, out);
}